// Round 7
// baseline (269.268 us; speedup 1.0000x reference)
//
#include <hip/hip_runtime.h>
#include <math.h>

#define B 1024
#define C 100000
#define D 64
#define TC 128                  // classes per chunk (one block per chunk)
#define NCH 782                 // ceil(C/TC); NCH*TC = 100096
#define NPADROWS (NCH * TC)
#define CPAD (NPADROWS - C)     // 96 zero pad rows
#define L2E 1.4426950408889634f

typedef __attribute__((ext_vector_type(8))) short short8;
typedef __attribute__((ext_vector_type(4))) float f32x4;

// ws byte layout:
//   WS_PART (6.4 MB) : s-partials float, 2 planes (ng) of [chunk][row]
//   WS_CW2  (4 KB)   : cw2[row] = -2*||x_row||*log2e
//   WS_XBF  (128 KB) : xs as bf16 [B][64]
#define WS_PART 0
#define WS_CW2  ((size_t)2 * NCH * B * 4)
#define WS_XBF  (WS_CW2 + B * 4)

#define GLB(p) ((const __attribute__((address_space(1))) void*)(p))
#define LDS(p) ((__attribute__((address_space(3))) void*)(p))

static __device__ __forceinline__ unsigned short f2bf(float f) {
    unsigned u = __float_as_uint(f);
    return (unsigned short)((u + 0x7fffu + ((u >> 16) & 1u)) >> 16);  // RNE
}
static __device__ __forceinline__ float bf_round(float f) {
    return __uint_as_float(((unsigned)f2bf(f)) << 16);
}
static __device__ __forceinline__ float fexp2(float x) {
#if __has_builtin(__builtin_amdgcn_exp2f)
    return __builtin_amdgcn_exp2f(x);
#else
    return __expf(x * 0.6931471805599453f);
#endif
}

// ---- tiny prep: xs -> bf16 + cw2 (0.4 MB traffic) ----
__global__ __launch_bounds__(256) void proxynca_prepx(
    const float* __restrict__ xs, unsigned short* __restrict__ Xbf,
    float* __restrict__ cw2)
{
    const int t = threadIdx.x;
    const int rl = t >> 4, f4 = t & 15;
    const int row = blockIdx.x * 16 + rl;
    const float4 v = *(const float4*)(xs + (size_t)row * D + f4 * 4);
    float ss = v.x*v.x + v.y*v.y + v.z*v.z + v.w*v.w;
    ss += __shfl_xor(ss, 1); ss += __shfl_xor(ss, 2);
    ss += __shfl_xor(ss, 4); ss += __shfl_xor(ss, 8);
    ushort4 w;
    w.x = f2bf(v.x); w.y = f2bf(v.y); w.z = f2bf(v.z); w.w = f2bf(v.w);
    *(ushort4*)(Xbf + (size_t)row * D + f4 * 4) = w;
    if (f4 == 0) cw2[row] = -2.0f * sqrtf(ss) * L2E;
}

// ---- main: one block per 128-class chunk; normalize once, sweep 1024 rows ----
__global__ __launch_bounds__(512, 6) void proxynca_main(
    const float* __restrict__ proxies, const unsigned short* __restrict__ Xbf,
    const float* __restrict__ cw2v, float* __restrict__ partial)
{
    __shared__ __align__(16) unsigned short Ash[256 * 64];   // 32 KB, swizzled
    __shared__ __align__(16) unsigned short Bsh[TC * 64];    // 16 KB, swizzled
    __shared__ __align__(16) float crow[B];                  // 4 KB

    const int t = threadIdx.x;                 // 0..511
    const int lane = t & 63;
    const int wv = t >> 6;                     // 0..7
    const int ct = blockIdx.x;                 // 0..781

    // DMA A tile 0 (Xbf rows 0..255); source-XOR-swizzle:
    // LDS chunk (row,p) holds global chunk (row, p^(row&7))
    #pragma unroll
    for (int j = 0; j < 4; ++j) {
        int c = (j * 8 + wv) * 64 + lane;
        int row = c >> 3, p = c & 7;
        int sc = (row << 3) | (p ^ (row & 7));
        __builtin_amdgcn_global_load_lds(GLB(Xbf + sc * 8),
            LDS(Ash + (size_t)(j * 8 + wv) * 512), 16, 0, 0);
    }
    // normalize this block's 128-class chunk ONCE into Bsh (bf16, swizzled)
    #pragma unroll
    for (int i = 0; i < 4; ++i) {
        int idx = i * 512 + t;
        int r = idx >> 4, f4 = idx & 15;       // r: 0..127
        int gc = ct * TC + r;
        float4 v = make_float4(0.f, 0.f, 0.f, 0.f);
        if (gc < C) v = *(const float4*)(proxies + (size_t)gc * D + f4 * 4);
        float ss = v.x*v.x + v.y*v.y + v.z*v.z + v.w*v.w;
        ss += __shfl_xor(ss, 1); ss += __shfl_xor(ss, 2);
        ss += __shfl_xor(ss, 4); ss += __shfl_xor(ss, 8);
        float rn = 1.0f / fmaxf(sqrtf(ss), 1e-12f);
        ushort4 w;
        w.x = f2bf(v.x * rn); w.y = f2bf(v.y * rn);
        w.z = f2bf(v.z * rn); w.w = f2bf(v.w * rn);
        int p = (f4 >> 1) ^ (r & 7);
        *(ushort4*)(Bsh + (size_t)((r * 8 + p) * 8 + (f4 & 1) * 4)) = w;
    }
    crow[t] = cw2v[t];
    crow[t + 512] = cw2v[t + 512];
    __syncthreads();                            // DMA tile0 + Bsh + crow visible

    const int quad = lane >> 4, sixt = lane & 15;
    const int mg = wv >> 1;                     // 0..3 : 64-row group
    const int ng = wv & 1;                      // 0..1 : 64-class group

    // B fragments in regs for the whole kernel; Bsh dead afterwards
    short8 bfr[4][2];
    #pragma unroll
    for (int ns = 0; ns < 4; ++ns) {
        int cl = ng * 64 + ns * 16 + sixt;
        int sw = cl & 7;
        bfr[ns][0] = *(const short8*)(Bsh + (size_t)(((cl << 3) | (quad ^ sw)) * 8));
        bfr[ns][1] = *(const short8*)(Bsh + (size_t)(((cl << 3) | ((4 + quad) ^ sw)) * 8));
    }

    float* plane = partial + (size_t)ng * NCH * B + (size_t)ct * B;

    for (int rt = 0; rt < 4; ++rt) {
        // fragment + cw reads from LDS for this 256-row tile
        short8 af[4][2];
        #pragma unroll
        for (int ms = 0; ms < 4; ++ms) {
            int rowL = mg * 64 + ms * 16 + sixt;
            int sw = rowL & 7;
            af[ms][0] = *(const short8*)(Ash + (size_t)(((rowL << 3) | (quad ^ sw)) * 8));
            af[ms][1] = *(const short8*)(Ash + (size_t)(((rowL << 3) | ((4 + quad) ^ sw)) * 8));
        }
        f32x4 cwv[4];
        #pragma unroll
        for (int ms = 0; ms < 4; ++ms)
            cwv[ms] = *(const f32x4*)(crow + rt * 256 + mg * 64 + ms * 16 + quad * 4);

        __syncthreads();                        // all waves done reading Ash

        if (rt < 3) {                           // DMA next 256-row tile (overwrite)
            const unsigned short* An = Xbf + (size_t)(rt + 1) * 256 * D;
            #pragma unroll
            for (int j = 0; j < 4; ++j) {
                int c = (j * 8 + wv) * 64 + lane;
                int row = c >> 3, p = c & 7;
                int sc = (row << 3) | (p ^ (row & 7));
                __builtin_amdgcn_global_load_lds(GLB(An + sc * 8),
                    LDS(Ash + (size_t)(j * 8 + wv) * 512), 16, 0, 0);
            }
        }

        float s_acc[4][4];
        #pragma unroll
        for (int ms = 0; ms < 4; ++ms)
            #pragma unroll
            for (int rgi = 0; rgi < 4; ++rgi) s_acc[ms][rgi] = 0.f;

        #pragma unroll
        for (int ns = 0; ns < 4; ++ns)
            #pragma unroll
            for (int ms = 0; ms < 4; ++ms) {
                f32x4 acc = {0.f, 0.f, 0.f, 0.f};
                acc = __builtin_amdgcn_mfma_f32_16x16x32_bf16(af[ms][0], bfr[ns][0], acc, 0, 0, 0);
                acc = __builtin_amdgcn_mfma_f32_16x16x32_bf16(af[ms][1], bfr[ns][1], acc, 0, 0, 0);
                #pragma unroll
                for (int rgi = 0; rgi < 4; ++rgi)
                    s_acc[ms][rgi] += fexp2(fmaf(2.0f * L2E, acc[rgi], cwv[ms][rgi]));
            }

        // 16-lane column reduce; lane sixt==0 of each quad holds 4 consecutive rows
        #pragma unroll
        for (int ms = 0; ms < 4; ++ms)
            #pragma unroll
            for (int rgi = 0; rgi < 4; ++rgi) {
                float s = s_acc[ms][rgi];
                s += __shfl_xor(s, 1); s += __shfl_xor(s, 2);
                s += __shfl_xor(s, 4); s += __shfl_xor(s, 8);
                s_acc[ms][rgi] = s;
            }
        if (sixt == 0) {
            #pragma unroll
            for (int ms = 0; ms < 4; ++ms) {
                f32x4 v = {s_acc[ms][0], s_acc[ms][1], s_acc[ms][2], s_acc[ms][3]};
                *(f32x4*)(plane + rt * 256 + mg * 64 + ms * 16 + quad * 4) = v;
            }
        }
        __syncthreads();                        // DMA drained; new tile visible
    }
}

// ---- fused: per-row partial sum + epilogue + mean (atomicAdd into zeroed out) ----
__global__ __launch_bounds__(256) void proxynca_reduce(
    const float* __restrict__ xs, const int* __restrict__ ys,
    const float* __restrict__ proxies, const float* __restrict__ partial,
    float* __restrict__ out)
{
    __shared__ float red[32][8];
    __shared__ float rowsumL[32];
    __shared__ float wacc[4];

    const int t = threadIdx.x;
    const int row0 = blockIdx.x * 32;
    const float* pl0 = partial;
    const float* pl1 = partial + (size_t)NCH * B;

    // phase 1: coalesced sum over chunks (lanes = consecutive rows)
    {
        const int rl = t & 31, pp = t >> 5;
        float s = 0.f;
        for (int j = pp; j < NCH; j += 8) {
            size_t o = (size_t)j * B + row0 + rl;
            s += pl0[o] + pl1[o];
        }
        red[rl][pp] = s;
    }
    __syncthreads();
    if (t < 32) {
        const float* r = red[t];
        rowsumL[t] = ((r[0] + r[1]) + (r[2] + r[3])) + ((r[4] + r[5]) + (r[6] + r[7]));
    }
    __syncthreads();

    // phase 2: per-row epilogue, 4 waves x 8 rows
    const int lane = t & 63, w = t >> 6;
    float myacc = 0.f;
    for (int i = 0; i < 8; ++i) {
        int rloc = w * 8 + i;
        int row = row0 + rloc;
        float x = xs[(size_t)row * D + lane];
        int y = ys[row];
        float p = proxies[(size_t)y * D + lane];

        float xx = x * x, pq = p * p;
        #pragma unroll
        for (int off = 1; off < 64; off <<= 1) {
            xx += __shfl_xor(xx, off);
            pq += __shfl_xor(pq, off);
        }
        float nx = sqrtf(xx);
        float rn = 1.0f / fmaxf(sqrtf(pq), 1e-12f);
        float ph = p * rn;

        float xp = x * ph;                       // exact fp32 dot for d_pos
        float xpb = bf_round(x) * bf_round(ph);  // bf16-matched dot for s subtraction
        #pragma unroll
        for (int off = 1; off < 64; off <<= 1) {
            xp  += __shfl_xor(xp, off);
            xpb += __shfl_xor(xpb, off);
        }
        if (lane == 0) {
            float s = rowsumL[rloc];
            float cw2r = -2.0f * nx * L2E;
            float e_pos = fexp2(fmaf(2.0f * L2E, xpb, cw2r));   // positive class
            float e_pad = fexp2(cw2r);                          // each zero pad row
            float s_neg = s - e_pos - (float)CPAD * e_pad;
            myacc += 2.0f * (nx - xp) + logf(s_neg);
        }
    }
    if (lane == 0) wacc[w] = myacc;
    __syncthreads();
    if (t == 0)
        atomicAdd(out, (wacc[0] + wacc[1] + wacc[2] + wacc[3]) * (1.0f / (float)B));
}

extern "C" void kernel_launch(void* const* d_in, const int* in_sizes, int n_in,
                              void* d_out, int out_size, void* d_ws, size_t ws_size,
                              hipStream_t stream)
{
    const float* xs      = (const float*)d_in[0];
    const int*   ys      = (const int*)d_in[1];
    const float* proxies = (const float*)d_in[2];
    char* ws = (char*)d_ws;
    float* partial = (float*)(ws + WS_PART);
    float* cw2     = (float*)(ws + WS_CW2);
    unsigned short* Xbf = (unsigned short*)(ws + WS_XBF);
    float* out = (float*)d_out;

    hipMemsetAsync(out, 0, sizeof(float), stream);
    proxynca_prepx<<<B / 16, 256, 0, stream>>>(xs, Xbf, cw2);
    proxynca_main<<<NCH, 512, 0, stream>>>(proxies, Xbf, cw2, partial);
    proxynca_reduce<<<B / 32, 256, 0, stream>>>(xs, ys, proxies, partial, out);
}

// Round 8
// 174.336 us; speedup vs baseline: 1.5445x; 1.5445x over previous
//
#include <hip/hip_runtime.h>
#include <math.h>

#define B 1024
#define C 100000
#define D 64
#define TC 128                  // classes per chunk
#define NCH 782                 // ceil(C/TC); NCH*TC = 100096
#define NPADROWS (NCH * TC)
#define CPAD (NPADROWS - C)     // 96 zero pad rows
#define L2E 1.4426950408889634f

typedef __attribute__((ext_vector_type(8))) short short8;
typedef __attribute__((ext_vector_type(4))) float f32x4;

// ws byte layout:
//   WS_PART (3.2 MB) : s-partials float [chunk][row]
//   WS_CW2  (4 KB)   : cw2[row] = -2*||x_row||*log2e
//   WS_XBF  (128 KB) : xs as bf16 [B][64]  (stays hot in L2)
#define WS_PART 0
#define WS_CW2  ((size_t)NCH * B * 4)
#define WS_XBF  (WS_CW2 + B * 4)

static __device__ __forceinline__ unsigned short f2bf(float f) {
    unsigned u = __float_as_uint(f);
    return (unsigned short)((u + 0x7fffu + ((u >> 16) & 1u)) >> 16);  // RNE
}
static __device__ __forceinline__ float bf_round(float f) {
    return __uint_as_float(((unsigned)f2bf(f)) << 16);
}
static __device__ __forceinline__ float fexp2(float x) {
#if __has_builtin(__builtin_amdgcn_exp2f)
    return __builtin_amdgcn_exp2f(x);
#else
    return __expf(x * 0.6931471805599453f);
#endif
}

// ---- tiny prep: xs -> bf16 + cw2 (0.4 MB traffic) ----
__global__ __launch_bounds__(256) void proxynca_prepx(
    const float* __restrict__ xs, unsigned short* __restrict__ Xbf,
    float* __restrict__ cw2)
{
    const int t = threadIdx.x;
    const int rl = t >> 4, f4 = t & 15;
    const int row = blockIdx.x * 16 + rl;
    const float4 v = *(const float4*)(xs + (size_t)row * D + f4 * 4);
    float ss = v.x*v.x + v.y*v.y + v.z*v.z + v.w*v.w;
    ss += __shfl_xor(ss, 1); ss += __shfl_xor(ss, 2);
    ss += __shfl_xor(ss, 4); ss += __shfl_xor(ss, 8);
    ushort4 w;
    w.x = f2bf(v.x); w.y = f2bf(v.y); w.z = f2bf(v.z); w.w = f2bf(v.w);
    *(ushort4*)(Xbf + (size_t)row * D + f4 * 4) = w;
    if (f4 == 0) cw2[row] = -2.0f * sqrtf(ss) * L2E;
}

// ---- main: 128 rows x 128 classes per 256-thread block; B in LDS, A from L2 ----
__global__ __launch_bounds__(256) void proxynca_main(
    const float* __restrict__ proxies, const unsigned short* __restrict__ Xbf,
    const float* __restrict__ cw2v, float* __restrict__ partial)
{
    __shared__ __align__(16) unsigned short Bsh[TC * 64];    // 16 KB, XOR-swizzled

    const int t = threadIdx.x;                 // 0..255
    const int lane = t & 63;
    const int wv = t >> 6;                     // 0..3
    const int bid = blockIdx.x;
    const int ct = bid >> 3;                   // 0..781 (chunk)
    const int rg = bid & 7;                    // 0..7   (row group) -> XCD spread
    const int row0 = rg * 128;
    const int col0 = ct * TC;

    // normalize this block's 128-class chunk into Bsh (bf16, XOR-swizzled)
    #pragma unroll
    for (int i = 0; i < 8; ++i) {
        int idx = i * 256 + t;
        int r = idx >> 4, f4 = idx & 15;       // r: 0..127
        int gc = col0 + r;
        float4 v = make_float4(0.f, 0.f, 0.f, 0.f);
        if (gc < C) v = *(const float4*)(proxies + (size_t)gc * D + f4 * 4);
        float ss = v.x*v.x + v.y*v.y + v.z*v.z + v.w*v.w;
        ss += __shfl_xor(ss, 1); ss += __shfl_xor(ss, 2);
        ss += __shfl_xor(ss, 4); ss += __shfl_xor(ss, 8);
        float rn = 1.0f / fmaxf(sqrtf(ss), 1e-12f);
        ushort4 w;
        w.x = f2bf(v.x * rn); w.y = f2bf(v.y * rn);
        w.z = f2bf(v.z * rn); w.w = f2bf(v.w * rn);
        int p = (f4 >> 1) ^ (r & 7);
        *(ushort4*)(Bsh + (size_t)((r * 8 + p) * 8 + (f4 & 1) * 4)) = w;
    }
    __syncthreads();                            // only barrier in the kernel

    const int quad = lane >> 4, sixt = lane & 15;
    const int mg = wv >> 1;                     // 0..1 : 64-row half
    const int ng = wv & 1;                      // 0..1 : 64-class half

    // B fragments resident in regs
    short8 bfr[4][2];
    #pragma unroll
    for (int ns = 0; ns < 4; ++ns) {
        int cl = ng * 64 + ns * 16 + sixt;
        int sw = cl & 7;
        bfr[ns][0] = *(const short8*)(Bsh + (size_t)(((cl << 3) | (quad ^ sw)) * 8));
        bfr[ns][1] = *(const short8*)(Bsh + (size_t)(((cl << 3) | ((4 + quad) ^ sw)) * 8));
    }

    float* pout = partial + (size_t)ct * B + row0;

    #pragma unroll
    for (int ms = 0; ms < 4; ++ms) {
        const int rloc = mg * 64 + ms * 16;     // local row base of this subtile
        // A fragment straight from global (L2-hot Xbf): 2 x 16B per lane
        const unsigned short* arow = Xbf + (size_t)(row0 + rloc + sixt) * D;
        short8 af0 = *(const short8*)(arow + quad * 8);
        short8 af1 = *(const short8*)(arow + 32 + quad * 8);
        f32x4 cw = *(const f32x4*)(cw2v + row0 + rloc + quad * 4);

        f32x4 s4 = {0.f, 0.f, 0.f, 0.f};
        #pragma unroll
        for (int ns = 0; ns < 4; ++ns) {
            f32x4 acc = {0.f, 0.f, 0.f, 0.f};
            acc = __builtin_amdgcn_mfma_f32_16x16x32_bf16(af0, bfr[ns][0], acc, 0, 0, 0);
            acc = __builtin_amdgcn_mfma_f32_16x16x32_bf16(af1, bfr[ns][1], acc, 0, 0, 0);
            // t_c = exp(2 x.p - 2||x||) = e^{-dist} * e^{(||x||-1)^2}  (<= ~1)
            #pragma unroll
            for (int rgi = 0; rgi < 4; ++rgi)
                s4[rgi] += fexp2(fmaf(2.0f * L2E, acc[rgi], cw[rgi]));
        }
        // 16-lane column reduce (ng planes combined later via +=? no: both ng
        // halves write distinct classes -> must be summed: do it with one
        // cross-wave pass through the partial array? Instead: atomic-free --
        // reduce within wave, then ng=1 wave adds via LDS after barrier-free
        // trick is unsafe; use global add: write ng=0, add ng=1? ordering race.
        // Solution: reduce over sixt AND fold ng by a second global pass is
        // avoided -- we simply let both ng-waves write disjoint slots below.
        #pragma unroll
        for (int off = 1; off < 16; off <<= 1)
            #pragma unroll
            for (int rgi = 0; rgi < 4; ++rgi)
                s4[rgi] += __shfl_xor(s4[rgi], off);
        if (sixt == 0)
            *(f32x4*)(pout + (size_t)ng * NCH * B + rloc + quad * 4) = s4;
    }
}

// ---- fused: per-row partial sum + epilogue + mean (atomicAdd into zeroed out) ----
__global__ __launch_bounds__(256) void proxynca_reduce(
    const float* __restrict__ xs, const int* __restrict__ ys,
    const float* __restrict__ proxies, const float* __restrict__ partial,
    float* __restrict__ out)
{
    __shared__ float red[32][8];
    __shared__ float rowsumL[32];
    __shared__ float wacc[4];

    const int t = threadIdx.x;
    const int row0 = blockIdx.x * 32;
    const float* pl0 = partial;
    const float* pl1 = partial + (size_t)NCH * B;

    // phase 1: coalesced sum over chunks (lanes = consecutive rows)
    {
        const int rl = t & 31, pp = t >> 5;
        float s = 0.f;
        for (int j = pp; j < NCH; j += 8) {
            size_t o = (size_t)j * B + row0 + rl;
            s += pl0[o] + pl1[o];
        }
        red[rl][pp] = s;
    }
    __syncthreads();
    if (t < 32) {
        const float* r = red[t];
        rowsumL[t] = ((r[0] + r[1]) + (r[2] + r[3])) + ((r[4] + r[5]) + (r[6] + r[7]));
    }
    __syncthreads();

    // phase 2: per-row epilogue, 4 waves x 8 rows
    const int lane = t & 63, w = t >> 6;
    float myacc = 0.f;
    for (int i = 0; i < 8; ++i) {
        int rloc = w * 8 + i;
        int row = row0 + rloc;
        float x = xs[(size_t)row * D + lane];
        int y = ys[row];
        float p = proxies[(size_t)y * D + lane];

        float xx = x * x, pq = p * p;
        #pragma unroll
        for (int off = 1; off < 64; off <<= 1) {
            xx += __shfl_xor(xx, off);
            pq += __shfl_xor(pq, off);
        }
        float nx = sqrtf(xx);
        float rn = 1.0f / fmaxf(sqrtf(pq), 1e-12f);
        float ph = p * rn;

        float xp = x * ph;                       // exact fp32 dot for d_pos
        float xpb = bf_round(x) * bf_round(ph);  // bf16-matched dot for s subtraction
        #pragma unroll
        for (int off = 1; off < 64; off <<= 1) {
            xp  += __shfl_xor(xp, off);
            xpb += __shfl_xor(xpb, off);
        }
        if (lane == 0) {
            float s = rowsumL[rloc];
            float cw2r = -2.0f * nx * L2E;
            float e_pos = fexp2(fmaf(2.0f * L2E, xpb, cw2r));   // positive class
            float e_pad = fexp2(cw2r);                          // each zero pad row
            float s_neg = s - e_pos - (float)CPAD * e_pad;
            myacc += 2.0f * (nx - xp) + logf(s_neg);
        }
    }
    if (lane == 0) wacc[w] = myacc;
    __syncthreads();
    if (t == 0)
        atomicAdd(out, (wacc[0] + wacc[1] + wacc[2] + wacc[3]) * (1.0f / (float)B));
}

extern "C" void kernel_launch(void* const* d_in, const int* in_sizes, int n_in,
                              void* d_out, int out_size, void* d_ws, size_t ws_size,
                              hipStream_t stream)
{
    const float* xs      = (const float*)d_in[0];
    const int*   ys      = (const int*)d_in[1];
    const float* proxies = (const float*)d_in[2];
    char* ws = (char*)d_ws;
    float* partial = (float*)(ws + WS_PART);     // NOTE: 2 planes used below
    float* cw2     = (float*)(ws + (size_t)2 * NCH * B * 4);
    unsigned short* Xbf = (unsigned short*)(ws + (size_t)2 * NCH * B * 4 + B * 4);
    float* out = (float*)d_out;

    hipMemsetAsync(out, 0, sizeof(float), stream);
    proxynca_prepx<<<B / 16, 256, 0, stream>>>(xs, Xbf, cw2);
    proxynca_main<<<NCH * 8, 256, 0, stream>>>(proxies, Xbf, cw2, partial);
    proxynca_reduce<<<B / 32, 256, 0, stream>>>(xs, ys, proxies, partial, out);
}